// Round 1
// 134.567 us; speedup vs baseline: 1.0574x; 1.0574x over previous
//
#include <hip/hip_runtime.h>

// BLS collapsed-iteration kernel.
// Key identity: W_{t+1} = c_t W_t - 2*LR*h1 (x) r_t stays in the family
//   W_t = P_t * W0 - 2*LR * h1 (x) (p_t*r0 + q_t*A)
// so the 100-step GD reduces to scalar recurrences per group.
//
// R3 post-mortem: fusing phase2 into phase1 via device-scope flags/fences
// regressed phase1 8x (122 us, 4% HBM) — cross-XCD atomic serialization +
// threadfence cache drains. Kept the 3-dispatch structure.
// R5 (this round): timed iteration is dominated by the harness's 256 MiB
// workspace poison fill (~41 us, top-5 counters are all fillBufferAligned).
// Controllable levers: (a) phase2's serial chain used precise sqrt+div on the
// loop-carried nsq path (~4 us whole-GPU bubble) -> v_rsq_f32 collapses it;
// (b) pred mat-vec moved out of p1pred into the phase2 dispatch so its 512
// waves hide under the recurrence latency instead of competing with phase1
// streaming.

typedef float f32x4 __attribute__((ext_vector_type(4)));

#define N1 192
#define N2 48
#define DIN 1024
#define DH 1025          // D_IN + 1
#define DOUT 512
#define LAMBDA 0.001f
#define LRATE 0.01f
#define NITR 100
#define DSPLIT 20
#define PER ((DH + DSPLIT - 1) / DSPLIT)   // 52
#define P1BLOCKS (N2 * DSPLIT)             // 960

// ---------------------------------------------------------------------------
// Kernel 1: phase-1 partial mat-vecs only (pure streamer, 960 blocks).
// Per group n and d-chunk:
//   pA[chunk][n][k] = sum_{d in chunk} h1[d] * We[n][d][k]
//   pS[chunk][n][k] = sum_{d in chunk} h1[d] * W0[n][d][k]
//   pN[chunk][n]    = sum_{d in chunk, k} W0[n][d][k]^2
__global__ __launch_bounds__(192) void p1(
    const float* __restrict__ x, const float* __restrict__ We,
    const float* __restrict__ W0, float* __restrict__ pA,
    float* __restrict__ pS, float* __restrict__ pN) {
  const int tid = threadIdx.x;
  const int n = blockIdx.x % N2;
  const int chunk = blockIdx.x / N2;
  const int d_lo = chunk * PER;
  const int d_hi = (d_lo + PER < DH) ? (d_lo + PER) : DH;
  const int r = tid / 48;
  const int c = tid % 48;
  const float4* We4 = (const float4*)(We + (size_t)n * DH * N1);
  const float4* W04 = (const float4*)(W0 + (size_t)n * DH * N1);
  float4 a = make_float4(0.f, 0.f, 0.f, 0.f);
  float4 s = make_float4(0.f, 0.f, 0.f, 0.f);
  float w2 = 0.f;
  for (int d = d_lo + r; d < d_hi; d += 4) {
    const float h = (d < DIN) ? x[d] : 1.0f;
    const float4 we = We4[d * 48 + c];
    const float4 w0 = W04[d * 48 + c];
    a.x += h * we.x; a.y += h * we.y; a.z += h * we.z; a.w += h * we.w;
    s.x += h * w0.x; s.y += h * w0.y; s.z += h * w0.z; s.w += h * w0.w;
    w2 += w0.x * w0.x + w0.y * w0.y + w0.z * w0.z + w0.w * w0.w;
  }
  __shared__ float4 shA[192];
  __shared__ float4 shS[192];
  __shared__ float red[192];
  shA[tid] = a; shS[tid] = s; red[tid] = w2;
  __syncthreads();
  if (tid < 48) {
    const float4 a0 = shA[tid], a1 = shA[tid + 48], a2 = shA[tid + 96], a3 = shA[tid + 144];
    const float4 s0 = shS[tid], s1 = shS[tid + 48], s2 = shS[tid + 96], s3 = shS[tid + 144];
    float4 ra, rs;
    ra.x = a0.x + a1.x + a2.x + a3.x; ra.y = a0.y + a1.y + a2.y + a3.y;
    ra.z = a0.z + a1.z + a2.z + a3.z; ra.w = a0.w + a1.w + a2.w + a3.w;
    rs.x = s0.x + s1.x + s2.x + s3.x; rs.y = s0.y + s1.y + s2.y + s3.y;
    rs.z = s0.z + s1.z + s2.z + s3.z; rs.w = s0.w + s1.w + s2.w + s3.w;
    ((float4*)(pA + ((size_t)chunk * N2 + n) * N1))[tid] = ra;
    ((float4*)(pS + ((size_t)chunk * N2 + n) * N1))[tid] = rs;
  }
  if (tid < 64) {
    float v = red[tid] + red[tid + 64] + red[tid + 128];
    #pragma unroll
    for (int o = 32; o; o >>= 1) v += __shfl_xor(v, o);
    if (tid == 0) pN[chunk * N2 + n] = v;
  }
}

// ---------------------------------------------------------------------------
// Kernel 2: blocks 0..47 run the per-group 100-step recurrence (serial scalar
// chain, v_rsq on the loop-carried path); blocks 48..559 each run one wave of
// the pred mat-vec (hidden under the recurrence latency).
__global__ __launch_bounds__(64) void phase2pred(
    const float* __restrict__ x,
    const float* __restrict__ pA, const float* __restrict__ pS,
    const float* __restrict__ pN, float* __restrict__ Pg,
    float* __restrict__ Rg, const float* __restrict__ Wp,
    const float* __restrict__ bp, float* __restrict__ pred_out) {
  const int lane = threadIdx.x;
  const float4* x4 = (const float4*)x;
  if (blockIdx.x >= N2) {
    // ---- pred: one wave per output row ----
    const int w = blockIdx.x - N2;
    const float4* row = (const float4*)(Wp + (size_t)w * DIN);
    float acc = 0.f;
    #pragma unroll
    for (int j = lane; j < DIN / 4; j += 64) {
      const float4 a = row[j];
      const float4 bx = x4[j];
      acc += a.x * bx.x + a.y * bx.y + a.z * bx.z + a.w * bx.w;
    }
    #pragma unroll
    for (int o = 32; o; o >>= 1) acc += __shfl_xor(acc, o);
    if (lane == 0) pred_out[w] = acc + bp[w];
    return;
  }
  const int n = blockIdx.x;
  float hn = 0.f;                           // ||h1||^2 partial (x part)
  #pragma unroll
  for (int j = lane; j < DIN / 4; j += 64) {
    const float4 v = x4[j];
    hn += v.x * v.x + v.y * v.y + v.z * v.z + v.w * v.w;
  }
  float A[3], S[3];
  #pragma unroll
  for (int j = 0; j < 3; ++j) {
    const int k = lane + 64 * j;
    float a = 0.f, s = 0.f;
    for (int ch = 0; ch < DSPLIT; ++ch) {
      a += pA[((size_t)ch * N2 + n) * N1 + k];
      s += pS[((size_t)ch * N2 + n) * N1 + k];
    }
    A[j] = a; S[j] = s;
  }
  float nsq = 0.f;
  for (int ch = 0; ch < DSPLIT; ++ch) nsq += pN[ch * N2 + n];
  float SA  = A[0] * A[0] + A[1] * A[1] + A[2] * A[2];   // ||A_raw||^2
  float S0A = S[0] * A[0] + S[1] * A[1] + S[2] * A[2];   // s0 . A_raw
  float S00 = S[0] * S[0] + S[1] * S[1] + S[2] * S[2];   // ||s0||^2
  #pragma unroll
  for (int o = 32; o; o >>= 1) {
    hn  += __shfl_xor(hn, o);
    SA  += __shfl_xor(SA, o);
    S0A += __shfl_xor(S0A, o);
    S00 += __shfl_xor(S00, o);
  }
  hn += 1.0f;                               // bias element of h1
  const float inv = 1.0f / sqrtf(SA);       // A = A_raw * inv
  const float AA  = SA * inv * inv;         // A.A  (~1)
  const float R0A = S0A * inv - AA;         // r0.A , r0 = s0 - A
  const float R00 = S00 - 2.f * S0A * inv + AA;  // r0.r0
  const float b = 2.f * LRATE;
  const float bh = b * hn;                  // loop-invariant
  float u = 1.f, v = 0.f, p = 0.f, q = 0.f, P = 1.f;
  for (int it = 0; it < NITR; ++it) {
    // v_rsq_f32 on the loop-carried nsq path: eps ~ 4e-8, 1-ulp approx error
    // perturbs c by ~1e-14 — far below the absmax budget.
    const float eps = (LRATE * LAMBDA) * __builtin_amdgcn_rsqf(nsq);
    const float c = 1.f - eps;
    const float alpha = c - bh;
    const float beta = -eps;
    // r_t = u*r0 + v*A  =>  dots:
    const float rr = u * u * R00 + 2.f * u * v * R0A + v * v * AA;
    const float ra = u * R0A + v * AA;
    const float rs = rr + ra;               // r.s with s = r + A
    nsq = c * c * nsq - 2.f * c * b * rs + b * b * hn * rr;
    p = c * p + u;  q = c * q + v;          // R_{t+1} = c R_t + r_t
    u = alpha * u;  v = alpha * v + beta;   // r_{t+1} = alpha r_t + beta A
    P *= c;
  }
  #pragma unroll
  for (int j = 0; j < 3; ++j) {
    const int k = lane + 64 * j;
    const float Aj = A[j] * inv;
    Rg[n * N1 + k] = p * (S[j] - Aj) + q * Aj;
  }
  if (lane == 0) Pg[n] = P;
}

// ---------------------------------------------------------------------------
// Epilogue: W_out[n][d][k] = P[n]*W0[n][d][k] - 2*LR*h1[d]*R[n][k]
// Two float4 elements per thread; non-temporal stores keep W0 (L3-warm from
// p1) resident during the wout pass itself.
#define NF4  ((unsigned)N2 * DH * 48)      // 2,361,600 float4s
#define HALF (NF4 / 2u)                    // 1,180,800
__global__ __launch_bounds__(256) void wout(
    const float* __restrict__ x, const float* __restrict__ W0,
    const float* __restrict__ Pg, const float* __restrict__ Rg,
    float* __restrict__ out) {
  const unsigned t = blockIdx.x * 256u + threadIdx.x;
  if (t >= HALF) return;
  #pragma unroll
  for (int half = 0; half < 2; ++half) {
    const unsigned i = t + half * HALF;
    const unsigned row = i / 48u;
    const unsigned c = i % 48u;
    const unsigned n = row / DH;
    const unsigned d = row % DH;
    const float h = (d < DIN) ? x[d] : 1.0f;
    const float4 w0 = ((const float4*)W0)[i];
    const float4 R4 = ((const float4*)Rg)[n * 48u + c];
    const float P = Pg[n];
    const float m = 2.f * LRATE * h;
    f32x4 o;
    o.x = P * w0.x - m * R4.x;
    o.y = P * w0.y - m * R4.y;
    o.z = P * w0.z - m * R4.z;
    o.w = P * w0.w - m * R4.w;
    __builtin_nontemporal_store(o, &((f32x4*)out)[i]);
  }
}

extern "C" void kernel_launch(void* const* d_in, const int* in_sizes, int n_in,
                              void* d_out, int out_size, void* d_ws, size_t ws_size,
                              hipStream_t stream) {
  const float* x  = (const float*)d_in[0];
  const float* We = (const float*)d_in[1];
  const float* W0 = (const float*)d_in[2];
  const float* Wp = (const float*)d_in[3];
  const float* bp = (const float*)d_in[4];
  float* out = (float*)d_out;
  float* ws = (float*)d_ws;
  // ws layout (floats); ~1.52 MB total
  float* pA = ws;
  float* pS = pA + (size_t)DSPLIT * N2 * N1;
  float* pN = pS + (size_t)DSPLIT * N2 * N1;
  float* Pg = pN + DSPLIT * N2;
  float* Rg = Pg + N2;

  p1<<<dim3(P1BLOCKS), dim3(192), 0, stream>>>(x, We, W0, pA, pS, pN);
  phase2pred<<<dim3(N2 + DOUT), dim3(64), 0, stream>>>(
      x, pA, pS, pN, Pg, Rg, Wp, bp, out);
  wout<<<dim3((HALF + 255u) / 256u), dim3(256), 0, stream>>>(x, W0, Pg, Rg, out + DOUT);
}

// Round 2
// 133.867 us; speedup vs baseline: 1.0630x; 1.0052x over previous
//
#include <hip/hip_runtime.h>

// BLS collapsed-iteration kernel.
// Key identity: W_{t+1} = c_t W_t - 2*LR*h1 (x) r_t stays in the family
//   W_t = P_t * W0 - 2*LR * h1 (x) (p_t*r0 + q_t*A)
// so the 100-step GD reduces to scalar recurrences per group.
//
// R3 post-mortem: device-scope flag/fence fusion regressed phase1 8x; keep
// the 3-dispatch structure.
// R5: rsq on the recurrence chain + pred moved under phase2's latency bubble
// (142.3 -> 134.6 us; matched prediction).
// R6 (this round): p1 was ~79% of achievable BW. Causes: runtime loop bounds
// blocked full unroll (too few loads in flight), and 960 blocks = 3.75/CU
// left a 6.7% scheduling tail. Reshape to 16 chunks x 64 rows (bias row 1024
// appended to chunk 15) -> static 16-trip unroll, no per-trip predicates,
// 768 blocks = exactly 3/CU.

typedef float f32x4 __attribute__((ext_vector_type(4)));

#define N1 192
#define N2 48
#define DIN 1024
#define DH 1025          // D_IN + 1
#define DOUT 512
#define LAMBDA 0.001f
#define LRATE 0.01f
#define NITR 100
#define NCH 16           // d-chunks of exactly 64 rows (bias row -> chunk 15)
#define P1BLOCKS (N2 * NCH)                // 768 = 3 blocks/CU exactly

// ---------------------------------------------------------------------------
// Kernel 1: phase-1 partial mat-vecs only (pure streamer, 768 blocks).
// Per group n and 64-row d-chunk:
//   pA[chunk][n][k] = sum_{d in chunk} h1[d] * We[n][d][k]
//   pS[chunk][n][k] = sum_{d in chunk} h1[d] * W0[n][d][k]
//   pN[chunk][n]    = sum_{d in chunk, k} W0[n][d][k]^2
__global__ __launch_bounds__(192) void p1(
    const float* __restrict__ x, const float* __restrict__ We,
    const float* __restrict__ W0, float* __restrict__ pA,
    float* __restrict__ pS, float* __restrict__ pN) {
  const int tid = threadIdx.x;
  const int n = blockIdx.x % N2;
  const int chunk = blockIdx.x / N2;
  const int r = tid / 48;                  // row-group 0..3
  const int c = tid % 48;                  // float4 column
  const float4* We4 = (const float4*)(We + (size_t)n * DH * N1);
  const float4* W04 = (const float4*)(W0 + (size_t)n * DH * N1);
  const int d0 = chunk * 64 + r;
  float4 a = make_float4(0.f, 0.f, 0.f, 0.f);
  float4 s = make_float4(0.f, 0.f, 0.f, 0.f);
  float w2 = 0.f;
  #pragma unroll
  for (int i = 0; i < 16; ++i) {
    const int d = d0 + 4 * i;              // always < 1024: no predicates
    const float h = x[d];
    const float4 we = We4[d * 48 + c];
    const float4 w0 = W04[d * 48 + c];
    a.x += h * we.x; a.y += h * we.y; a.z += h * we.z; a.w += h * we.w;
    s.x += h * w0.x; s.y += h * w0.y; s.z += h * w0.z; s.w += h * w0.w;
    w2 += w0.x * w0.x + w0.y * w0.y + w0.z * w0.z + w0.w * w0.w;
  }
  if (chunk == NCH - 1 && r == 0) {
    // bias row d = 1024, h = 1
    const float4 we = We4[1024 * 48 + c];
    const float4 w0 = W04[1024 * 48 + c];
    a.x += we.x; a.y += we.y; a.z += we.z; a.w += we.w;
    s.x += w0.x; s.y += w0.y; s.z += w0.z; s.w += w0.w;
    w2 += w0.x * w0.x + w0.y * w0.y + w0.z * w0.z + w0.w * w0.w;
  }
  __shared__ float4 shA[192];
  __shared__ float4 shS[192];
  __shared__ float red[192];
  shA[tid] = a; shS[tid] = s; red[tid] = w2;
  __syncthreads();
  if (tid < 48) {
    const float4 a0 = shA[tid], a1 = shA[tid + 48], a2 = shA[tid + 96], a3 = shA[tid + 144];
    const float4 s0 = shS[tid], s1 = shS[tid + 48], s2 = shS[tid + 96], s3 = shS[tid + 144];
    float4 ra, rs;
    ra.x = a0.x + a1.x + a2.x + a3.x; ra.y = a0.y + a1.y + a2.y + a3.y;
    ra.z = a0.z + a1.z + a2.z + a3.z; ra.w = a0.w + a1.w + a2.w + a3.w;
    rs.x = s0.x + s1.x + s2.x + s3.x; rs.y = s0.y + s1.y + s2.y + s3.y;
    rs.z = s0.z + s1.z + s2.z + s3.z; rs.w = s0.w + s1.w + s2.w + s3.w;
    ((float4*)(pA + ((size_t)chunk * N2 + n) * N1))[tid] = ra;
    ((float4*)(pS + ((size_t)chunk * N2 + n) * N1))[tid] = rs;
  }
  if (tid < 64) {
    float v = red[tid] + red[tid + 64] + red[tid + 128];
    #pragma unroll
    for (int o = 32; o; o >>= 1) v += __shfl_xor(v, o);
    if (tid == 0) pN[chunk * N2 + n] = v;
  }
}

// ---------------------------------------------------------------------------
// Kernel 2: blocks 0..47 run the per-group 100-step recurrence (serial scalar
// chain, v_rsq on the loop-carried path); blocks 48..559 each run one wave of
// the pred mat-vec (hidden under the recurrence latency).
__global__ __launch_bounds__(64) void phase2pred(
    const float* __restrict__ x,
    const float* __restrict__ pA, const float* __restrict__ pS,
    const float* __restrict__ pN, float* __restrict__ Pg,
    float* __restrict__ Rg, const float* __restrict__ Wp,
    const float* __restrict__ bp, float* __restrict__ pred_out) {
  const int lane = threadIdx.x;
  const float4* x4 = (const float4*)x;
  if (blockIdx.x >= N2) {
    // ---- pred: one wave per output row ----
    const int w = blockIdx.x - N2;
    const float4* row = (const float4*)(Wp + (size_t)w * DIN);
    float acc = 0.f;
    #pragma unroll
    for (int j = lane; j < DIN / 4; j += 64) {
      const float4 a = row[j];
      const float4 bx = x4[j];
      acc += a.x * bx.x + a.y * bx.y + a.z * bx.z + a.w * bx.w;
    }
    #pragma unroll
    for (int o = 32; o; o >>= 1) acc += __shfl_xor(acc, o);
    if (lane == 0) pred_out[w] = acc + bp[w];
    return;
  }
  const int n = blockIdx.x;
  float hn = 0.f;                           // ||h1||^2 partial (x part)
  #pragma unroll
  for (int j = lane; j < DIN / 4; j += 64) {
    const float4 v = x4[j];
    hn += v.x * v.x + v.y * v.y + v.z * v.z + v.w * v.w;
  }
  float A[3], S[3];
  #pragma unroll
  for (int j = 0; j < 3; ++j) {
    const int k = lane + 64 * j;
    float a = 0.f, s = 0.f;
    for (int ch = 0; ch < NCH; ++ch) {
      a += pA[((size_t)ch * N2 + n) * N1 + k];
      s += pS[((size_t)ch * N2 + n) * N1 + k];
    }
    A[j] = a; S[j] = s;
  }
  float nsq = 0.f;
  for (int ch = 0; ch < NCH; ++ch) nsq += pN[ch * N2 + n];
  float SA  = A[0] * A[0] + A[1] * A[1] + A[2] * A[2];   // ||A_raw||^2
  float S0A = S[0] * A[0] + S[1] * A[1] + S[2] * A[2];   // s0 . A_raw
  float S00 = S[0] * S[0] + S[1] * S[1] + S[2] * S[2];   // ||s0||^2
  #pragma unroll
  for (int o = 32; o; o >>= 1) {
    hn  += __shfl_xor(hn, o);
    SA  += __shfl_xor(SA, o);
    S0A += __shfl_xor(S0A, o);
    S00 += __shfl_xor(S00, o);
  }
  hn += 1.0f;                               // bias element of h1
  const float inv = 1.0f / sqrtf(SA);       // A = A_raw * inv
  const float AA  = SA * inv * inv;         // A.A  (~1)
  const float R0A = S0A * inv - AA;         // r0.A , r0 = s0 - A
  const float R00 = S00 - 2.f * S0A * inv + AA;  // r0.r0
  const float b = 2.f * LRATE;
  const float bh = b * hn;                  // loop-invariant
  float u = 1.f, v = 0.f, p = 0.f, q = 0.f, P = 1.f;
  for (int it = 0; it < NITR; ++it) {
    // v_rsq_f32 on the loop-carried nsq path: eps ~ 4e-8, 1-ulp approx error
    // perturbs c by ~1e-14 — far below the absmax budget.
    const float eps = (LRATE * LAMBDA) * __builtin_amdgcn_rsqf(nsq);
    const float c = 1.f - eps;
    const float alpha = c - bh;
    const float beta = -eps;
    // r_t = u*r0 + v*A  =>  dots:
    const float rr = u * u * R00 + 2.f * u * v * R0A + v * v * AA;
    const float ra = u * R0A + v * AA;
    const float rs = rr + ra;               // r.s with s = r + A
    nsq = c * c * nsq - 2.f * c * b * rs + b * b * hn * rr;
    p = c * p + u;  q = c * q + v;          // R_{t+1} = c R_t + r_t
    u = alpha * u;  v = alpha * v + beta;   // r_{t+1} = alpha r_t + beta A
    P *= c;
  }
  #pragma unroll
  for (int j = 0; j < 3; ++j) {
    const int k = lane + 64 * j;
    const float Aj = A[j] * inv;
    Rg[n * N1 + k] = p * (S[j] - Aj) + q * Aj;
  }
  if (lane == 0) Pg[n] = P;
}

// ---------------------------------------------------------------------------
// Epilogue: W_out[n][d][k] = P[n]*W0[n][d][k] - 2*LR*h1[d]*R[n][k]
// Two float4 elements per thread; non-temporal stores; W0 is L3-warm from p1.
#define NF4  ((unsigned)N2 * DH * 48)      // 2,361,600 float4s
#define HALF (NF4 / 2u)                    // 1,180,800
__global__ __launch_bounds__(256) void wout(
    const float* __restrict__ x, const float* __restrict__ W0,
    const float* __restrict__ Pg, const float* __restrict__ Rg,
    float* __restrict__ out) {
  const unsigned t = blockIdx.x * 256u + threadIdx.x;
  if (t >= HALF) return;
  #pragma unroll
  for (int half = 0; half < 2; ++half) {
    const unsigned i = t + half * HALF;
    const unsigned row = i / 48u;
    const unsigned c = i % 48u;
    const unsigned n = row / DH;
    const unsigned d = row % DH;
    const float h = (d < DIN) ? x[d] : 1.0f;
    const float4 w0 = ((const float4*)W0)[i];
    const float4 R4 = ((const float4*)Rg)[n * 48u + c];
    const float P = Pg[n];
    const float m = 2.f * LRATE * h;
    f32x4 o;
    o.x = P * w0.x - m * R4.x;
    o.y = P * w0.y - m * R4.y;
    o.z = P * w0.z - m * R4.z;
    o.w = P * w0.w - m * R4.w;
    __builtin_nontemporal_store(o, &((f32x4*)out)[i]);
  }
}

extern "C" void kernel_launch(void* const* d_in, const int* in_sizes, int n_in,
                              void* d_out, int out_size, void* d_ws, size_t ws_size,
                              hipStream_t stream) {
  const float* x  = (const float*)d_in[0];
  const float* We = (const float*)d_in[1];
  const float* W0 = (const float*)d_in[2];
  const float* Wp = (const float*)d_in[3];
  const float* bp = (const float*)d_in[4];
  float* out = (float*)d_out;
  float* ws = (float*)d_ws;
  // ws layout (floats); ~1.2 MB total
  float* pA = ws;
  float* pS = pA + (size_t)NCH * N2 * N1;
  float* pN = pS + (size_t)NCH * N2 * N1;
  float* Pg = pN + NCH * N2;
  float* Rg = Pg + N2;

  p1<<<dim3(P1BLOCKS), dim3(192), 0, stream>>>(x, We, W0, pA, pS, pN);
  phase2pred<<<dim3(N2 + DOUT), dim3(64), 0, stream>>>(
      x, pA, pS, pN, Pg, Rg, Wp, bp, out);
  wout<<<dim3((HALF + 255u) / 256u), dim3(256), 0, stream>>>(x, W0, Pg, Rg, out + DOUT);
}